// Round 6
// baseline (197.090 us; speedup 1.0000x reference)
//
#include <hip/hip_runtime.h>
#include <hip/hip_bf16.h>
#include <stdint.h>

// HyperbolicAttention MI355X implementation.
// B=2, N=4096, D_IN=256, UNITS=512, H=8, depth=64.
// Round 6: attention = round-2 geometry (4 waves x 32-q strips: best LDS reuse) +
// round-5 VALU diet (exp2 fold, cvt_pk, ones-MFMA denominator) + j-split x2
// (grid 1024 -> 3 blocks/CU) with f32 partial O/den and a combine kernel.

typedef __attribute__((ext_vector_type(8))) short short8;
typedef __attribute__((ext_vector_type(4))) short short4v;
typedef __attribute__((ext_vector_type(4))) float f32x4;
typedef __attribute__((ext_vector_type(2))) unsigned int u32x2;
typedef __attribute__((ext_vector_type(4))) unsigned int u32x4;

#define DEVFN static __device__ __forceinline__

DEVFN unsigned short f2bf(float f) {
  unsigned u = __float_as_uint(f);
  u += 0x7FFFu + ((u >> 16) & 1u);   // RNE
  return (unsigned short)(u >> 16);
}

DEVFN void mfma16(f32x4& d, short8 a, short8 b) {
  d = __builtin_amdgcn_mfma_f32_16x16x32_bf16(a, b, d, 0, 0, 0);
}

DEVFN void gload_lds16(const void* g, void* l) {
  __builtin_amdgcn_global_load_lds((__attribute__((address_space(1))) void*)g,
                                   (__attribute__((address_space(3))) void*)l, 16, 0, 0);
}
DEVFN void gload_lds4(const void* g, void* l) {
  __builtin_amdgcn_global_load_lds((__attribute__((address_space(1))) void*)g,
                                   (__attribute__((address_space(3))) void*)l, 4, 0, 0);
}

// ---------------- weight convert + transpose to BT layout (bf16) ----------------
__global__ __launch_bounds__(256) void wconv_kernel(const float* Wq, const float* Wk,
                                                    const float* Wv, const float* Wo,
                                                    unsigned short* wqkvT, unsigned short* woT) {
  int t = blockIdx.x * 256 + threadIdx.x;
  if (t < 1536 * 256) {
    int nn = t >> 8, kk = t & 255;
    int which = nn >> 9, n2 = nn & 511;
    const float* W = (which == 0) ? Wq : (which == 1) ? Wk : Wv;
    wqkvT[t] = f2bf(W[kk * 512 + n2]);
  }
  int t2 = t - 1536 * 256;
  if (t2 >= 0 && t2 < 512 * 512) {
    int nn = t2 >> 9, kk = t2 & 511;
    woT[t2] = f2bf(Wo[kk * 512 + nn]);
  }
}

// ---------------- tangent = logmap0(inputs), bf16 [8192][256] ----------------
__global__ __launch_bounds__(256) void tangent_kernel(const float* x, unsigned short* tang) {
  const int row = blockIdx.x;
  const int tid = threadIdx.x;
  float v = x[(size_t)row * 256 + tid];
  float ss = v * v;
  #pragma unroll
  for (int m = 1; m <= 32; m <<= 1) ss += __shfl_xor(ss, m, 64);
  __shared__ __align__(16) float red[4];
  if ((tid & 63) == 0) red[tid >> 6] = ss;
  __syncthreads();
  float tot = (red[0] + red[1]) + (red[2] + red[3]);
  float n = fmaxf(sqrtf(tot), 1e-7f);
  float arg = fminf(n, 1.0f - 1e-5f);
  float scale = atanhf(arg) / n;
  tang[(size_t)row * 256 + tid] = f2bf(v * scale);
}

// ---------------- GEMM: C[M][N] f32 = A[M][K]bf16 @ B, B given as BT[N][K]bf16 ----------------
__global__ __launch_bounds__(256) void gemm_bt(const unsigned short* A, const unsigned short* BT,
                                               float* C, int M, int N, int K, int NB) {
  __shared__ __align__(16) unsigned short As[2][64 * 64];
  __shared__ __align__(16) unsigned short Bs[2][64 * 64];
  const int tid = threadIdx.x;
  const int l = tid & 63, w = tid >> 6;
  const int g = l >> 4, i = l & 15;
  const int bm = blockIdx.x / NB, bn = blockIdx.x % NB;
  const int m0 = bm << 6, n0 = bn << 6;
  const int wm = w >> 1, wn = w & 1;
  f32x4 acc[2][2] = {};

  const int NK = K >> 6;
  auto stage = [&](int kc, int bb) {
    const int kb = kc << 6;
    #pragma unroll
    for (int inst = 0; inst < 2; ++inst) {
      int o = (w << 11) + (inst << 10) + (l << 4);
      int row = o >> 7;
      int gG = ((o >> 4) & 7) ^ (row & 7);
      gload_lds16(A + ((size_t)(m0 + row) * K + kb + gG * 8),
                  (char*)&As[bb][0] + (w << 11) + (inst << 10));
      gload_lds16(BT + ((size_t)(n0 + row) * K + kb + gG * 8),
                  (char*)&Bs[bb][0] + (w << 11) + (inst << 10));
    }
  };
  stage(0, 0);
  __syncthreads();
  for (int kc = 0; kc < NK; ++kc) {
    const int bb = kc & 1;
    if (kc + 1 < NK) stage(kc + 1, bb ^ 1);
    #pragma unroll
    for (int hh = 0; hh < 2; ++hh) {
      short8 af[2], bf[2];
      #pragma unroll
      for (int mt = 0; mt < 2; ++mt) {
        int row = (wm << 5) + (mt << 4) + i;
        af[mt] = *(const short8*)((const char*)&As[bb][0] + (row << 7) +
                                  ((((hh << 2) + g) ^ (row & 7)) << 4));
      }
      #pragma unroll
      for (int nt = 0; nt < 2; ++nt) {
        int row = (wn << 5) + (nt << 4) + i;
        bf[nt] = *(const short8*)((const char*)&Bs[bb][0] + (row << 7) +
                                  ((((hh << 2) + g) ^ (row & 7)) << 4));
      }
      #pragma unroll
      for (int mt = 0; mt < 2; ++mt)
        #pragma unroll
        for (int nt = 0; nt < 2; ++nt)
          mfma16(acc[mt][nt], af[mt], bf[nt]);
    }
    __syncthreads();
  }
  #pragma unroll
  for (int mt = 0; mt < 2; ++mt)
    #pragma unroll
    for (int nt = 0; nt < 2; ++nt)
      #pragma unroll
      for (int r = 0; r < 4; ++r) {
        int row = m0 + (wm << 5) + (mt << 4) + (g << 2) + r;
        int col = n0 + (wn << 5) + (nt << 4) + i;
        C[(size_t)row * N + col] = acc[mt][nt][r];
      }
}

// ---------------- per-head hyperbolic maps ----------------
__global__ __launch_bounds__(256) void hyp_kernel(const float* qkv, unsigned short* qh,
                                                  unsigned short* kh, unsigned short* vT,
                                                  float* k2lT) {
  __shared__ __align__(16) unsigned short vt_t[64][72];
  const int tid = threadIdx.x;
  const int l = tid & 63, w = tid >> 6;
  const int bh = blockIdx.x & 15, nt = blockIdx.x >> 4;
  const int b = bh >> 3, h = bh & 7;
  const int n0 = nt << 6;
  const int d = l;
  for (int r = 0; r < 16; ++r) {
    int n = n0 + w * 16 + r;
    size_t base = (size_t)(b * 4096 + n) * 1536 + h * 64 + d;
    float qv = qkv[base], kv = qkv[base + 512], vv = qkv[base + 1024];
    float sq = qv * qv, sk = kv * kv, sv = vv * vv;
    #pragma unroll
    for (int m = 1; m <= 32; m <<= 1) {
      sq += __shfl_xor(sq, m, 64);
      sk += __shfl_xor(sk, m, 64);
      sv += __shfl_xor(sv, m, 64);
    }
    float nq = fmaxf(sqrtf(sq), 1e-7f);
    float qs = tanhf(nq) / nq;
    float nk = fmaxf(sqrtf(sk), 1e-7f);
    float tk = tanhf(nk);
    float ks = tk / nk;
    float nv = fmaxf(sqrtf(sv), 1e-7f);
    float vs = atanhf(fminf(nv, 1.0f - 1e-5f)) / nv;
    size_t ob = (size_t)(b * 4096 + n) * 512 + h * 64 + d;
    qh[ob] = f2bf(qv * qs);
    kh[ob] = f2bf(kv * ks);
    if (d == 0) k2lT[(size_t)bh * 4096 + n] = tk * tk * 0.125f * 1.4426950408889634f;
    vt_t[d][w * 16 + r] = f2bf(vv * vs);
  }
  __syncthreads();
  const int dd = tid >> 2, p = tid & 3;
  u32x4 a0 = *(const u32x4*)&vt_t[dd][p * 16];
  u32x4 a1 = *(const u32x4*)&vt_t[dd][p * 16 + 8];
  size_t vb = (size_t)(bh * 64 + dd) * 4096 + n0 + p * 16;
  *(u32x4*)(vT + vb) = a0;
  *(u32x4*)(vT + vb + 8) = a1;
}

// ---------------- attention (partial, j-split) ----------------
// Grid 1024 = (bh[4b], qt[5b], half[1b]). 256 threads = 4 waves; wave w owns q-strip
// [qt*128 + w*32, +32) (2 sub-strips of 16). Block processes j in [half*2048, +2048).
// K/V/k2 staged global->LDS double-buffered (shared by all waves; 32-q strips give 2x
// fragment reuse vs 16-q). Logits*log2e = S*CQK - k2l; no max needed (bounded).
// Swapped QK^T: S^T = mfma(K,Q). P via wave-private LDS transpose. Denominator =
// mfma(P, ONES) - identical path to numerator. Outputs UNNORMALIZED partial O (f32)
// and partial den; combine_kernel merges the two j-halves and normalizes.
__global__ __launch_bounds__(256) void attn_kernel(const unsigned short* __restrict__ qhG,
                                                   const unsigned short* __restrict__ khG,
                                                   const unsigned short* __restrict__ vTG,
                                                   const float* __restrict__ k2lG,
                                                   float* __restrict__ opart,
                                                   float* __restrict__ denpart) {
  __shared__ __align__(16) unsigned short Kbuf[2][64 * 64];
  __shared__ __align__(16) unsigned short Vbuf[2][64 * 64];
  __shared__ __align__(16) float k2buf[2][64];
  __shared__ __align__(16) unsigned short Pbuf[4][2][16 * 40];  // [wave][strip][16q][32+8 pad]

  const int tid = threadIdx.x;
  const int l = tid & 63, w = tid >> 6;
  const int g = l >> 4, i = l & 15;
  const int p = blockIdx.x;
  const int bh = p & 15, qt = (p >> 4) & 31, half = p >> 9;
  const int b = bh >> 3, h = bh & 7;
  const int qbase = qt * 128 + w * 32;
  const int j0 = half * 2048;

  const short8 ONES = {16256, 16256, 16256, 16256, 16256, 16256, 16256, 16256};  // bf16 1.0
  const float CQK = 0.36067376022224087f;  // 0.25 * log2(e)

  // resident Q fragments (B-frag of swapped QK mfma): per strip s, rows q = i.
  short8 qf[2][2];
  #pragma unroll
  for (int s = 0; s < 2; ++s)
    #pragma unroll
    for (int hh = 0; hh < 2; ++hh)
      qf[s][hh] = *(const short8*)(qhG + (size_t)(b * 4096 + qbase + s * 16 + i) * 512 +
                                   h * 64 + hh * 32 + g * 8);

  f32x4 acc[2][4] = {};    // [s][ds]: row q = g*4+r, col d = ds*16+i
  f32x4 accden[2] = {};    // [s] rowsum via ones-MFMA, same row map

  auto stage = [&](int jc, int bb) {
    const int jb = jc << 6;
    #pragma unroll
    for (int inst = 0; inst < 2; ++inst) {
      int o = (w << 11) + (inst << 10) + (l << 4);
      int row = o >> 7;
      int gG = ((o >> 4) & 7) ^ (row & 7);
      gload_lds16(khG + ((size_t)(b * 4096 + j0 + jb + row) * 512 + h * 64 + gG * 8),
                  (char*)&Kbuf[bb][0] + (w << 11) + (inst << 10));
      gload_lds16(vTG + ((size_t)(bh * 64 + row) * 4096 + j0 + jb + gG * 8),
                  (char*)&Vbuf[bb][0] + (w << 11) + (inst << 10));
    }
    if (tid < 64) gload_lds4(k2lG + (size_t)bh * 4096 + j0 + jb + tid, (char*)&k2buf[bb][0]);
  };

  stage(0, 0);
  __syncthreads();

  for (int jc = 0; jc < 32; ++jc) {
    const int bb = jc & 1;
    if (jc + 1 < 32) stage(jc + 1, bb ^ 1);
    const char* Kb = (const char*)&Kbuf[bb][0];
    const char* Vb = (const char*)&Vbuf[bb][0];

    #pragma unroll
    for (int u = 0; u < 2; ++u) {          // 32-j sub-chunk
      #pragma unroll
      for (int t = 0; t < 2; ++t) {        // 16-j tile
        const int jt = u * 2 + t;
        const int krow = jt * 16 + i;
        const int sw = (krow & 7) << 4;
        short8 kf0 = *(const short8*)(Kb + (krow << 7) + ((g << 4) ^ sw));
        short8 kf1 = *(const short8*)(Kb + (krow << 7) + (((g + 4) << 4) ^ sw));
        f32x4 k2v = *(const f32x4*)&k2buf[bb][jt * 16 + (g << 2)];
        #pragma unroll
        for (int s = 0; s < 2; ++s) {
          f32x4 S = {0.f, 0.f, 0.f, 0.f};
          mfma16(S, kf0, qf[s][0]);
          mfma16(S, kf1, qf[s][1]);
          f32x4 pr;
          #pragma unroll
          for (int r = 0; r < 4; ++r)
            pr[r] = __builtin_amdgcn_exp2f(fmaf(S[r], CQK, -k2v[r]));
          __hip_bfloat162 lo = __float22bfloat162_rn(make_float2(pr[0], pr[1]));
          __hip_bfloat162 hi = __float22bfloat162_rn(make_float2(pr[2], pr[3]));
          unsigned lo_u, hi_u;
          __builtin_memcpy(&lo_u, &lo, 4);
          __builtin_memcpy(&hi_u, &hi, 4);
          u32x2 pk;
          pk[0] = lo_u;
          pk[1] = hi_u;
          *(u32x2*)((char*)&Pbuf[w][s][0] + i * 80 + t * 32 + g * 8) = pk;
        }
      }
      short8 pf[2];
      #pragma unroll
      for (int s = 0; s < 2; ++s) {
        pf[s] = *(const short8*)((const char*)&Pbuf[w][s][0] + i * 80 + g * 16);
        mfma16(accden[s], pf[s], ONES);
      }
      #pragma unroll
      for (int ds = 0; ds < 4; ++ds) {
        const int vrow = ds * 16 + i;
        const int c = u * 4 + g;
        short8 vf = *(const short8*)(Vb + (vrow << 7) + ((c ^ (vrow & 7)) << 4));
        #pragma unroll
        for (int s = 0; s < 2; ++s)
          mfma16(acc[s][ds], pf[s], vf);
      }
    }
    __syncthreads();
  }

  // partial epilogue: unnormalized O (f32) + row denominators
  float* ob = opart + (size_t)half * (8192 * 512);
  #pragma unroll
  for (int s = 0; s < 2; ++s) {
    #pragma unroll
    for (int ds = 0; ds < 4; ++ds)
      #pragma unroll
      for (int r = 0; r < 4; ++r) {
        int row = qbase + s * 16 + (g << 2) + r;
        ob[(size_t)(b * 4096 + row) * 512 + h * 64 + ds * 16 + i] = acc[s][ds][r];
      }
    if (i == 0) {
      #pragma unroll
      for (int r = 0; r < 4; ++r) {
        int row = qbase + s * 16 + (g << 2) + r;
        denpart[half * 65536 + bh * 4096 + row] = accden[s][r];
      }
    }
  }
}

// ---------------- combine: ctx = (O0+O1) / (d0+d1), bf16 ----------------
__global__ __launch_bounds__(256) void combine_kernel(const float* __restrict__ opart,
                                                      const float* __restrict__ denpart,
                                                      unsigned short* __restrict__ ctx) {
  const int idx = blockIdx.x * 256 + threadIdx.x;   // 1,048,576 f32x4 groups
  const int row = idx >> 7;
  const int g4 = (idx & 127) << 2;
  const int b = row >> 12, q = row & 4095;
  const int bh = b * 8 + (g4 >> 6);
  const float den = denpart[bh * 4096 + q] + denpart[65536 + bh * 4096 + q];
  const float inv = 1.0f / den;
  const size_t off = (size_t)row * 512 + g4;
  f32x4 o0 = *(const f32x4*)(opart + off);
  f32x4 o1 = *(const f32x4*)(opart + 4194304 + off);
  __hip_bfloat162 lo = __float22bfloat162_rn(make_float2((o0[0] + o1[0]) * inv,
                                                         (o0[1] + o1[1]) * inv));
  __hip_bfloat162 hi = __float22bfloat162_rn(make_float2((o0[2] + o1[2]) * inv,
                                                         (o0[3] + o1[3]) * inv));
  unsigned lo_u, hi_u;
  __builtin_memcpy(&lo_u, &lo, 4);
  __builtin_memcpy(&hi_u, &hi, 4);
  u32x2 pk;
  pk[0] = lo_u;
  pk[1] = hi_u;
  *(u32x2*)(ctx + off) = pk;
}

// ---------------- final expmap0 over 512-dim rows ----------------
__global__ __launch_bounds__(256) void final_kernel(const float* xin, float* out) {
  const int row = blockIdx.x;
  const int tid = threadIdx.x;
  const float* xr = xin + (size_t)row * 512;
  float v0 = xr[tid], v1 = xr[tid + 256];
  float ss = v0 * v0 + v1 * v1;
  #pragma unroll
  for (int m = 1; m <= 32; m <<= 1) ss += __shfl_xor(ss, m, 64);
  __shared__ __align__(16) float red[4];
  if ((tid & 63) == 0) red[tid >> 6] = ss;
  __syncthreads();
  float tot = (red[0] + red[1]) + (red[2] + red[3]);
  float n = fmaxf(sqrtf(tot), 1e-7f);
  float sc = tanhf(n) / n;
  out[(size_t)row * 512 + tid] = v0 * sc;
  out[(size_t)row * 512 + tid + 256] = v1 * sc;
}

// ---------------- launch ----------------
extern "C" void kernel_launch(void* const* d_in, const int* in_sizes, int n_in,
                              void* d_out, int out_size, void* d_ws, size_t ws_size,
                              hipStream_t stream) {
  const float* inputs = (const float*)d_in[0];
  const float* Wq = (const float*)d_in[1];
  const float* Wk = (const float*)d_in[2];
  const float* Wv = (const float*)d_in[3];
  const float* Wo = (const float*)d_in[4];
  float* out = (float*)d_out;
  char* ws = (char*)d_ws;

  // workspace layout (~79.25 MB peak):
  //  [0,48M):  qkv f32 [8192][1536] during proj; after hyp dead. Reuse:
  //    ctx bf16 @0 (8M); opart f32 [2][8192][512] @8M (32M, dead after combine);
  //    out_pre f32 @8M (16M, written after combine over dead opart)
  //  [48M): k2lT f32 (256K); [49M): denpart f32 [2][65536] (512K)
  //  [53M): wqkvT (0.75M); [54M): woT (0.5M)
  //  [55M): qh (8M); [63M): kh (8M); [71M): vT (8M)    (tang @48M during proj)
  float* qkv            = (float*)(ws);
  unsigned short* ctx   = (unsigned short*)(ws);
  float* opart          = (float*)(ws + ((size_t)8 << 20));
  float* out_pre        = (float*)(ws + ((size_t)8 << 20));
  unsigned short* tang  = (unsigned short*)(ws + ((size_t)48 << 20));
  float* k2lT           = (float*)(ws + ((size_t)48 << 20));
  float* denpart        = (float*)(ws + ((size_t)49 << 20));
  unsigned short* wqkvT = (unsigned short*)(ws + ((size_t)53 << 20));
  unsigned short* woT   = (unsigned short*)(ws + ((size_t)54 << 20));
  unsigned short* qh    = (unsigned short*)(ws + ((size_t)55 << 20));
  unsigned short* kh    = (unsigned short*)(ws + ((size_t)63 << 20));
  unsigned short* vT    = (unsigned short*)(ws + ((size_t)71 << 20));

  wconv_kernel<<<2560, 256, 0, stream>>>(Wq, Wk, Wv, Wo, wqkvT, woT);
  tangent_kernel<<<8192, 256, 0, stream>>>(inputs, tang);
  gemm_bt<<<128 * 24, 256, 0, stream>>>(tang, wqkvT, qkv, 8192, 1536, 256, 24);
  hyp_kernel<<<1024, 256, 0, stream>>>(qkv, qh, kh, vT, k2lT);
  attn_kernel<<<1024, 256, 0, stream>>>(qh, kh, vT, k2lT, opart, denpart);
  combine_kernel<<<4096, 256, 0, stream>>>(opart, denpart, ctx);
  gemm_bt<<<128 * 8, 256, 0, stream>>>(ctx, woT, out_pre, 8192, 512, 512, 8);
  final_kernel<<<8192, 256, 0, stream>>>(out_pre, out);
}